// Round 21
// baseline (117.554 us; speedup 1.0000x reference)
//
#include <hip/hip_runtime.h>
#include <math.h>

#define N_ 8
#define F_ 64
#define P_ 25
#define H_ 6
#define D_ 192
#define HD_ 32
#define T_ 1600
#define SC2F 0.25503486f   // SCALE * log2(e)

typedef short bf16x8 __attribute__((ext_vector_type(8)));
typedef float f32x4 __attribute__((ext_vector_type(4)));
typedef unsigned int uint4v __attribute__((ext_vector_type(4)));

__device__ __forceinline__ unsigned short f2bf(float f) {
    unsigned int u = __float_as_uint(f);
    u += 0x7fffu + ((u >> 16) & 1u);
    return (unsigned short)(u >> 16);
}
__device__ __forceinline__ float bf2f(unsigned short s) {
    return __uint_as_float(((unsigned int)s) << 16);
}
__device__ __forceinline__ unsigned int pack2bf(float lo, float hi) {
    return (unsigned int)f2bf(lo) | ((unsigned int)f2bf(hi) << 16);
}
__device__ __forceinline__ unsigned int cvt_pk_bf16(float lo, float hi) {
    unsigned int r;
    asm("v_cvt_pk_bf16_f32 %0, %1, %2" : "=v"(r) : "v"(lo), "v"(hi));
    return r;
}

// ---------------------------------------------------------------------------
// Kernel 0 (merged): blocks 0-131 = bias MLP tables (pre-scaled by SC2F);
// blocks 132-156 = onehot A-fragment table; blocks 157-300 = bf16 weight
// conversion (qkv_w then proj_w).
// ---------------------------------------------------------------------------
__global__ __launch_bounds__(256) void prep_kernel(
    const float* __restrict__ t_w1, const float* __restrict__ t_b1,
    const float* __restrict__ t_w2, const float* __restrict__ t_b2,
    const float* __restrict__ h_w1, const float* __restrict__ h_b1,
    const float* __restrict__ h_w2, const float* __restrict__ h_b2,
    const float* __restrict__ qkv_w, const float* __restrict__ proj_w,
    float* __restrict__ tt, float* __restrict__ th,
    unsigned int* __restrict__ augA,
    unsigned short* __restrict__ wb, unsigned short* __restrict__ pwb)
{
    int b = blockIdx.x;
    if (b >= 157) {               // weight conversion part
        int idx = (b - 157) * 1024 + threadIdx.x * 4;
        const float* src;
        unsigned short* dst;
        if (idx < 110592) { src = qkv_w + idx; dst = wb + idx; }
        else { idx -= 110592; if (idx >= 36864) return; src = proj_w + idx; dst = pwb + idx; }
        float4 v = *(const float4*)src;
        uint2 pk;
        pk.x = pack2bf(v.x, v.y);
        pk.y = pack2bf(v.z, v.w);
        *(uint2*)dst = pk;
        return;
    }
    if (b >= 132) {               // aug table part
        int tau = b - 132;
        int sb = threadIdx.x >> 6, lane = threadIdx.x & 63;
        int g = lane >> 4, qi = lane & 15;
        int s = tau * 64 + sb * 16 + qi;
        int fs = (s * 5243) >> 17;
        int ps = s - fs * 25;
        int fs0 = ((tau * 64) * 5243) >> 17;
        int dfs = fs - fs0;
        unsigned int a[4];
        #pragma unroll
        for (int jj = 0; jj < 4; ++jj) {
            int k0 = g * 8 + 2 * jj, k1 = k0 + 1;
            bool c0 = (k0 < 4) ? (dfs == k0) : (ps == k0 - 4);
            bool c1 = (k1 < 4) ? (dfs == k1) : (ps == k1 - 4);
            a[jj] = (c0 ? 0x3F80u : 0u) | (c1 ? 0x3F800000u : 0u);
        }
        uint4v w = {a[0], a[1], a[2], a[3]};
        *(uint4v*)&augA[((size_t)(tau * 4 + sb) * 64 + lane) * 4] = w;
        return;
    }
    __shared__ float hid[192];
    bool is_t = (b < 127);
    float pos = is_t ? (float)(b - 63) : (float)(b - 127);
    const float* w1 = is_t ? t_w1 : h_w1;
    const float* b1 = is_t ? t_b1 : h_b1;
    const float* w2 = is_t ? t_w2 : h_w2;
    const float* b2 = is_t ? t_b2 : h_b2;
    int t = threadIdx.x;
    if (t < 192) hid[t] = fmaxf(pos * w1[t] + b1[t], 0.0f);
    __syncthreads();
    if (t < 6) {
        float s = b2[t];
        for (int j = 0; j < 192; ++j) s += w2[t * 192 + j] * hid[j];
        s *= SC2F;
        if (is_t) tt[t * 127 + b] = s;
        else      th[t * 5 + (b - 127)] = s;
    }
}

// ---------------------------------------------------------------------------
// Kernel 1: QKV projection, bf16 MFMA GEMM. Weights pre-converted to bf16.
// Q pre-scaled by SC2F.
// ---------------------------------------------------------------------------
__global__ __launch_bounds__(256) void qkv_gemm_kernel(
    const float* __restrict__ x, const unsigned short* __restrict__ wb,
    unsigned short* __restrict__ qout, unsigned short* __restrict__ kout,
    unsigned short* __restrict__ vout)
{
    __shared__ __align__(16) unsigned short alds[64][200];
    __shared__ __align__(16) unsigned short blds[64][72];

    int b = blockIdx.x;
    int bm = b % 200, bn = b / 200;
    int row0 = bm * 64, col0 = bn * 64;
    int tid = threadIdx.x, lane = tid & 63, wv = tid >> 6;
    int g = lane >> 4, qi = lane & 15;

    #pragma unroll
    for (int p = 0; p < 12; ++p) {
        int fid = tid + p * 256;
        int r = fid / 48, c4 = (fid % 48) * 4;
        float4 a4 = *(const float4*)&x[(size_t)(row0 + r) * 192 + c4];
        uint2 pk;
        pk.x = pack2bf(a4.x, a4.y);
        pk.y = pack2bf(a4.z, a4.w);
        *(uint2*)&alds[r][c4] = pk;
    }

    f32x4 acc[4];
    #pragma unroll
    for (int nt = 0; nt < 4; ++nt) acc[nt] = (f32x4){0.f, 0.f, 0.f, 0.f};

    for (int k0 = 0; k0 < 192; k0 += 64) {
        __syncthreads();
        #pragma unroll
        for (int p = 0; p < 2; ++p) {
            int fid = tid + p * 256;
            int j = fid >> 3, kk = (fid & 7) * 8;
            *(uint4*)&blds[j][kk] =
                *(const uint4*)&wb[(size_t)(col0 + j) * 192 + k0 + kk];
        }
        __syncthreads();
        #pragma unroll
        for (int ks = 0; ks < 2; ++ks) {
            bf16x8 af = *(const bf16x8*)&alds[wv * 16 + qi][k0 + ks * 32 + g * 8];
            #pragma unroll
            for (int nt = 0; nt < 4; ++nt) {
                bf16x8 bf = *(const bf16x8*)&blds[nt * 16 + qi][ks * 32 + g * 8];
                acc[nt] = __builtin_amdgcn_mfma_f32_16x16x32_bf16(af, bf, acc[nt], 0, 0, 0);
            }
        }
    }

    #pragma unroll
    for (int nt = 0; nt < 4; ++nt) {
        int col = col0 + nt * 16 + qi;
        int three = col / 192;
        int rem = col - three * 192;
        int h = rem >> 5, c = rem & 31;
        unsigned short* dst = (three == 0) ? qout : ((three == 1) ? kout : vout);
        float scl = (three == 0) ? SC2F : 1.0f;
        #pragma unroll
        for (int r = 0; r < 4; ++r) {
            int row = row0 + wv * 16 + 4 * g + r;
            int n = row / 1600, t = row - n * 1600;
            dst[((size_t)(n * 6 + h) * 1600 + t) * 32 + c] = f2bf(acc[nt][r] * scl);
        }
    }
}

// ---------------------------------------------------------------------------
// Kernel 2: fused attention + relational epilogue (R19 structure restored:
// if(more)-guarded prefetch). v_perm V-packing, sigma-permuted V^T,
// register-resident P, l via ones-MFMA.
// ---------------------------------------------------------------------------
__global__ __launch_bounds__(256) void attn_kernel(
    const unsigned short* __restrict__ qw, const unsigned short* __restrict__ kw,
    const unsigned short* __restrict__ vw, const float* __restrict__ tt,
    const float* __restrict__ th, const int* __restrict__ hops,
    const unsigned int* __restrict__ augA, const float* __restrict__ outer,
    const float* __restrict__ alpha_p, unsigned short* __restrict__ comb)
{
    __shared__ __align__(16) unsigned short ks[2][64][40];   // K, padded rows
    __shared__ __align__(16) unsigned int vts32[2][32][34];  // V^T, sigma-permuted s-pairs
    __shared__ unsigned int tthi[127], ttlo[127];

    int b = blockIdx.x;
    int serial = (b & 7) * 150 + (b >> 3);   // XCD-contiguous nh chunks
    int nh = serial / 25;
    int qt = serial % 25;
    int h = nh % 6;
    int n = nh / 6;
    int t0 = qt * 64;

    int tid = threadIdx.x;
    int lane = tid & 63, wv = tid >> 6;
    int g = lane >> 4, qi = lane & 15;
    int i = tid & 127;
    bool isK = (wv < 2);

    const unsigned short* qb = qw + (size_t)nh * 51200;
    const unsigned short* kb = kw + (size_t)nh * 51200;
    const unsigned short* vb = vw + (size_t)nh * 51200;

    if (tid < 127) {   // inline ttl hi/lo packing
        float a = tt[h * 127 + tid];
        float bm1 = tt[h * 127 + max(tid - 1, 0)];
        unsigned short ha = f2bf(a), hb = f2bf(bm1);
        tthi[tid] = (unsigned)ha | ((unsigned)hb << 16);
        ttlo[tid] = (unsigned)f2bf(a - bf2f(ha)) |
                    ((unsigned)f2bf(bm1 - bf2f(hb)) << 16);
    }

    int tq = t0 + wv * 16 + qi;
    int ft = (tq * 5243) >> 17;
    int pt = tq - ft * 25;

    bf16x8 qfrag = *(const bf16x8*)&qb[(size_t)tq * 32 + g * 8];

    // static part of B_aug (hop bias, pre-scaled th), hi+lo split
    unsigned int baug_hi[4], baug_lo[4];
    #pragma unroll
    for (int jj = 0; jj < 4; ++jj) {
        int k0 = g * 8 + 2 * jj, k1 = k0 + 1;
        float v0 = 0.f, v1 = 0.f;
        if (k0 >= 4 && k0 < 29) v0 = th[h * 5 + hops[pt * 25 + (k0 - 4)]];
        if (k1 >= 4 && k1 < 29) v1 = th[h * 5 + hops[pt * 25 + (k1 - 4)]];
        unsigned short h0 = f2bf(v0), h1 = f2bf(v1);
        unsigned short l0 = f2bf(v0 - bf2f(h0)), l1 = f2bf(v1 - bf2f(h1));
        baug_hi[jj] = (unsigned)h0 | ((unsigned)h1 << 16);
        baug_lo[jj] = (unsigned)l0 | ((unsigned)l1 << 16);
    }

    f32x4 O0 = {0.f, 0.f, 0.f, 0.f}, O1 = {0.f, 0.f, 0.f, 0.f};
    f32x4 Lacc = {0.f, 0.f, 0.f, 0.f};
    uint4v onesu = {0x3F803F80u, 0x3F803F80u, 0x3F803F80u, 0x3F803F80u};
    bf16x8 onesf = __builtin_bit_cast(bf16x8, onesu);

    const uint4v* augp = (const uint4v*)augA;

    // V staging: sigma-permuted column index (bijective in [0,32))
    int vp = i >> 2, vc8 = (i & 3) * 8;
    int up = (vp & 16) | ((vp & 6) << 1) | ((vp & 8) >> 2) | (vp & 1);
    int krow = i >> 1, kc16 = (i & 1) * 16;

    // ---- prologue: stage tile 0 into buffer 0 ----
    if (isK) {
        const unsigned short* src = kb + (size_t)krow * 32 + kc16;
        uint4 a = *(const uint4*)src;
        uint4 bq = *(const uint4*)(src + 8);
        *(uint4*)&ks[0][krow][kc16] = a;
        *(uint4*)&ks[0][krow][kc16 + 8] = bq;
    } else {
        const unsigned short* src = vb + (size_t)(2 * vp) * 32 + vc8;
        uint4 a = *(const uint4*)src;
        uint4 c = *(const uint4*)(src + 32);
        unsigned int av[4] = {a.x, a.y, a.z, a.w};
        unsigned int cv[4] = {c.x, c.y, c.z, c.w};
        #pragma unroll
        for (int jj = 0; jj < 4; ++jj) {
            vts32[0][vc8 + 2 * jj][up] =
                __builtin_amdgcn_perm(cv[jj], av[jj], 0x05040100u);
            vts32[0][vc8 + 2 * jj + 1][up] =
                __builtin_amdgcn_perm(cv[jj], av[jj], 0x07060302u);
        }
    }
    uint4v augr[4];
    #pragma unroll
    for (int sb = 0; sb < 4; ++sb) augr[sb] = augp[(size_t)sb * 64 + lane];
    __syncthreads();

    for (int tau = 0; tau < 25; ++tau) {
        int cur = tau & 1, nxt = cur ^ 1;
        int s0 = tau * 64;
        bool more = (tau < 24);

        // issue next tile's loads early
        uint4 r0 = {0, 0, 0, 0}, r1 = {0, 0, 0, 0};
        uint4v augn[4];
        if (more) {
            if (isK) {
                const unsigned short* src = kb + (size_t)(s0 + 64 + krow) * 32 + kc16;
                r0 = *(const uint4*)src;
                r1 = *(const uint4*)(src + 8);
            } else {
                const unsigned short* src = vb + (size_t)(s0 + 64 + 2 * vp) * 32 + vc8;
                r0 = *(const uint4*)src;
                r1 = *(const uint4*)(src + 32);
            }
            #pragma unroll
            for (int sb = 0; sb < 4; ++sb)
                augn[sb] = augp[(size_t)((tau + 1) * 4 + sb) * 64 + lane];
        }

        int fs0 = (s0 * 5243) >> 17;

        // dynamic ttl slots of B_aug from packed tables (g==0 lanes)
        unsigned int bh0 = baug_hi[0], bh1 = baug_hi[1];
        unsigned int bl0 = baug_lo[0], bl1 = baug_lo[1];
        if (g == 0) {
            int base = ft - fs0 + 63;
            bh0 = tthi[base]; bh1 = tthi[base - 2];
            bl0 = ttlo[base]; bl1 = ttlo[base - 2];
        }
        uint4v bhiu = {bh0, bh1, baug_hi[2], baug_hi[3]};
        uint4v blou = {bl0, bl1, baug_lo[2], baug_lo[3]};
        bf16x8 bhif = __builtin_bit_cast(bf16x8, bhiu);
        bf16x8 blof = __builtin_bit_cast(bf16x8, blou);

        // QK^T + bias via table-driven aug-MFMA
        f32x4 sfr[4];
        #pragma unroll
        for (int sb = 0; sb < 4; ++sb) {
            bf16x8 af = __builtin_bit_cast(bf16x8, augr[sb]);
            bf16x8 kf = *(const bf16x8*)&ks[cur][sb * 16 + qi][g * 8];
            f32x4 cz = {0.f, 0.f, 0.f, 0.f};
            f32x4 cb = __builtin_amdgcn_mfma_f32_16x16x32_bf16(af, blof, cz, 0, 0, 0);
            cb = __builtin_amdgcn_mfma_f32_16x16x32_bf16(af, bhif, cb, 0, 0, 0);
            sfr[sb] = __builtin_amdgcn_mfma_f32_16x16x32_bf16(kf, qfrag, cb, 0, 0, 0);
        }

        // unnormalized softmax: p = 2^sfr; keep packed P in registers
        uint2 pkk[4];
        #pragma unroll
        for (int sb = 0; sb < 4; ++sb) {
            float p0 = __builtin_exp2f(sfr[sb][0]);
            float p1 = __builtin_exp2f(sfr[sb][1]);
            float p2 = __builtin_exp2f(sfr[sb][2]);
            float p3 = __builtin_exp2f(sfr[sb][3]);
            pkk[sb].x = cvt_pk_bf16(p0, p1);
            pkk[sb].y = cvt_pk_bf16(p2, p3);
        }

        // stage-writes for tau+1 BEFORE PV
        if (more) {
            if (isK) {
                *(uint4*)&ks[nxt][krow][kc16] = r0;
                *(uint4*)&ks[nxt][krow][kc16 + 8] = r1;
            } else {
                unsigned int av[4] = {r0.x, r0.y, r0.z, r0.w};
                unsigned int cv[4] = {r1.x, r1.y, r1.z, r1.w};
                #pragma unroll
                for (int jj = 0; jj < 4; ++jj) {
                    vts32[nxt][vc8 + 2 * jj][up] =
                        __builtin_amdgcn_perm(cv[jj], av[jj], 0x05040100u);
                    vts32[nxt][vc8 + 2 * jj + 1][up] =
                        __builtin_amdgcn_perm(cv[jj], av[jj], 0x07060302u);
                }
            }
            #pragma unroll
            for (int sb = 0; sb < 4; ++sb) augr[sb] = augn[sb];
        }

        #pragma unroll
        for (int c = 0; c < 2; ++c) {
            uint4v pau = {pkk[2 * c].x, pkk[2 * c].y, pkk[2 * c + 1].x, pkk[2 * c + 1].y};
            bf16x8 paf = __builtin_bit_cast(bf16x8, pau);
            uint2 la = *(const uint2*)&vts32[cur][qi][c * 16 + 4 * g];
            uint2 lb = *(const uint2*)&vts32[cur][qi][c * 16 + 4 * g + 2];
            uint2 ha = *(const uint2*)&vts32[cur][16 + qi][c * 16 + 4 * g];
            uint2 hb = *(const uint2*)&vts32[cur][16 + qi][c * 16 + 4 * g + 2];
            uint4v u0 = {la.x, la.y, lb.x, lb.y};
            uint4v u1 = {ha.x, ha.y, hb.x, hb.y};
            bf16x8 v0f = __builtin_bit_cast(bf16x8, u0);
            bf16x8 v1f = __builtin_bit_cast(bf16x8, u1);
            O0 = __builtin_amdgcn_mfma_f32_16x16x32_bf16(paf, v0f, O0, 0, 0, 0);
            O1 = __builtin_amdgcn_mfma_f32_16x16x32_bf16(paf, v1f, O1, 0, 0, 0);
            Lacc = __builtin_amdgcn_mfma_f32_16x16x32_bf16(paf, onesf, Lacc, 0, 0, 0);
        }

        __syncthreads();
    }

    // ---- fused relational epilogue ----
    // Overlay outer[h] (25x26 f32) + V rows (100x32 bf16) onto dead ks buffer.
    float* olds = (float*)&ks[0][0][0];                       // 2600 B
    unsigned short* vl = (unsigned short*)((char*)&ks[0][0][0] + 2720);
    unsigned int* vl32 = (unsigned int*)vl;
    const unsigned int* vb32 = (const unsigned int*)vb;
    int f_lo = (t0 * 5243) >> 17;

    for (int e = tid; e < 625; e += 256)
        olds[(e / 25) * 26 + (e % 25)] = outer[h * 625 + e];
    for (int w = tid; w < 1600; w += 256) {
        int row = w >> 4, c2 = w & 15;
        int grow = min(f_lo * 25 + row, 1599);
        vl32[row * 16 + c2] = vb32[(size_t)grow * 16 + c2];
    }
    __syncthreads();

    float alpha = alpha_p[0];
    int trow = t0 + wv * 16;
    #pragma unroll
    for (int r = 0; r < 4; ++r) {
        float wr = alpha / Lacc[r];
        int t = trow + 4 * g + r;
        int ftt = (t * 5243) >> 17;
        int ptt = t - ftt * 25;
        int vbr = (ftt - f_lo) * 25;
        float rel0 = 0.f, rel1 = 0.f;
        #pragma unroll
        for (int q = 0; q < 25; ++q) {
            float ow = olds[ptt * 26 + q];
            rel0 += ow * bf2f(vl[(vbr + q) * 32 + qi]);
            rel1 += ow * bf2f(vl[(vbr + q) * 32 + 16 + qi]);
        }
        size_t cb = ((size_t)(n * 1600 + t)) * 192 + h * 32;
        comb[cb + qi] = f2bf(O0[r] * wr + rel0);
        comb[cb + 16 + qi] = f2bf(O1[r] * wr + rel1);
    }
}

// ---------------------------------------------------------------------------
// Kernel 3: final projection, bf16 MFMA GEMM. Weights pre-converted to bf16.
// ---------------------------------------------------------------------------
__global__ __launch_bounds__(256) void proj_gemm_kernel(
    const unsigned short* __restrict__ comb, const unsigned short* __restrict__ pwb,
    const float* __restrict__ pb, float* __restrict__ out)
{
    __shared__ __align__(16) unsigned short alds[64][200];
    __shared__ __align__(16) unsigned short blds[64][72];

    int b = blockIdx.x;
    int bm = b % 200, bn = b / 200;
    int row0 = bm * 64, col0 = bn * 64;
    int tid = threadIdx.x, lane = tid & 63, wv = tid >> 6;
    int g = lane >> 4, qi = lane & 15;

    #pragma unroll
    for (int p = 0; p < 6; ++p) {
        int fid = tid + p * 256;
        int r = fid / 24, c8 = (fid % 24) * 8;
        *(uint4*)&alds[r][c8] = *(const uint4*)&comb[(size_t)(row0 + r) * 192 + c8];
    }

    f32x4 acc[4];
    #pragma unroll
    for (int nt = 0; nt < 4; ++nt) acc[nt] = (f32x4){0.f, 0.f, 0.f, 0.f};

    for (int k0 = 0; k0 < 192; k0 += 64) {
        __syncthreads();
        #pragma unroll
        for (int p = 0; p < 2; ++p) {
            int fid = tid + p * 256;
            int j = fid >> 3, kk = (fid & 7) * 8;
            *(uint4*)&blds[j][kk] =
                *(const uint4*)&pwb[(size_t)(col0 + j) * 192 + k0 + kk];
        }
        __syncthreads();
        #pragma unroll
        for (int ks = 0; ks < 2; ++ks) {
            bf16x8 af = *(const bf16x8*)&alds[wv * 16 + qi][k0 + ks * 32 + g * 8];
            #pragma unroll
            for (int nt = 0; nt < 4; ++nt) {
                bf16x8 bf = *(const bf16x8*)&blds[nt * 16 + qi][ks * 32 + g * 8];
                acc[nt] = __builtin_amdgcn_mfma_f32_16x16x32_bf16(af, bf, acc[nt], 0, 0, 0);
            }
        }
    }

    #pragma unroll
    for (int nt = 0; nt < 4; ++nt) {
        int col = col0 + nt * 16 + qi;
        float bias = pb[col];
        #pragma unroll
        for (int r = 0; r < 4; ++r) {
            int row = row0 + wv * 16 + 4 * g + r;
            out[(size_t)row * 192 + col] = acc[nt][r] + bias;
        }
    }
}

// ---------------------------------------------------------------------------
extern "C" void kernel_launch(void* const* d_in, const int* in_sizes, int n_in,
                              void* d_out, int out_size, void* d_ws, size_t ws_size,
                              hipStream_t stream)
{
    const float* x      = (const float*)d_in[0];
    const float* qkv_w  = (const float*)d_in[1];
    const float* proj_w = (const float*)d_in[2];
    const float* proj_b = (const float*)d_in[3];
    const float* t_w1   = (const float*)d_in[4];
    const float* t_b1   = (const float*)d_in[5];
    const float* t_w2   = (const float*)d_in[6];
    const float* t_b2   = (const float*)d_in[7];
    const float* h_w1   = (const float*)d_in[8];
    const float* h_b1   = (const float*)d_in[9];
    const float* h_w2   = (const float*)d_in[10];
    const float* h_b2   = (const float*)d_in[11];
    const float* outer  = (const float*)d_in[12];
    const float* alpha  = (const float*)d_in[13];
    const int*   hops   = (const int*)d_in[14];
    float* out = (float*)d_out;

    char* w8 = (char*)d_ws;
    float* tt = (float*)w8;                                  // 762 f @ 0
    float* th = (float*)(w8 + 3072);                         // 30 f
    unsigned int* augA = (unsigned int*)(w8 + 10240);        // 102400 B
    unsigned short* wb  = (unsigned short*)(w8 + 112640);    // 221184 B
    unsigned short* pwb = (unsigned short*)(w8 + 333824);    // 73728 B
    unsigned short* qb = (unsigned short*)(w8 + 409600);
    unsigned short* kb = qb + 2457600;
    unsigned short* vb = kb + 2457600;
    unsigned short* comb = (unsigned short*)(w8 + 409600 + 3 * 4915200);

    prep_kernel<<<301, 256, 0, stream>>>(t_w1, t_b1, t_w2, t_b2,
                                         h_w1, h_b1, h_w2, h_b2,
                                         qkv_w, proj_w, tt, th, augA, wb, pwb);
    qkv_gemm_kernel<<<1800, 256, 0, stream>>>(x, wb, qb, kb, vb);
    attn_kernel<<<1200, 256, 0, stream>>>(qb, kb, vb, tt, th, hops, augA,
                                          outer, alpha, comb);
    proj_gemm_kernel<<<600, 256, 0, stream>>>(comb, pwb, proj_b, out);
}

// Round 22
// 92.678 us; speedup vs baseline: 1.2684x; 1.2684x over previous
//
#include <hip/hip_runtime.h>
#include <math.h>

#define N_ 8
#define F_ 64
#define P_ 25
#define H_ 6
#define D_ 192
#define HD_ 32
#define T_ 1600
#define SC2F 0.25503486f   // SCALE * log2(e)

typedef short bf16x8 __attribute__((ext_vector_type(8)));
typedef float f32x4 __attribute__((ext_vector_type(4)));
typedef unsigned int uint4v __attribute__((ext_vector_type(4)));

__device__ __forceinline__ unsigned short f2bf(float f) {
    unsigned int u = __float_as_uint(f);
    u += 0x7fffu + ((u >> 16) & 1u);
    return (unsigned short)(u >> 16);
}
__device__ __forceinline__ float bf2f(unsigned short s) {
    return __uint_as_float(((unsigned int)s) << 16);
}
__device__ __forceinline__ unsigned int pack2bf(float lo, float hi) {
    return (unsigned int)f2bf(lo) | ((unsigned int)f2bf(hi) << 16);
}
__device__ __forceinline__ unsigned int cvt_pk_bf16(float lo, float hi) {
    unsigned int r;
    asm("v_cvt_pk_bf16_f32 %0, %1, %2" : "=v"(r) : "v"(lo), "v"(hi));
    return r;
}

// ---------------------------------------------------------------------------
// Kernel 0 (merged): blocks 0-131 = bias MLP tables (pre-scaled by SC2F);
// blocks 132-156 = onehot A-fragment table; blocks 157-300 = bf16 weight
// conversion (qkv_w then proj_w).
// ---------------------------------------------------------------------------
__global__ __launch_bounds__(256) void prep_kernel(
    const float* __restrict__ t_w1, const float* __restrict__ t_b1,
    const float* __restrict__ t_w2, const float* __restrict__ t_b2,
    const float* __restrict__ h_w1, const float* __restrict__ h_b1,
    const float* __restrict__ h_w2, const float* __restrict__ h_b2,
    const float* __restrict__ qkv_w, const float* __restrict__ proj_w,
    float* __restrict__ tt, float* __restrict__ th,
    unsigned int* __restrict__ augA,
    unsigned short* __restrict__ wb, unsigned short* __restrict__ pwb)
{
    int b = blockIdx.x;
    if (b >= 157) {               // weight conversion part
        int idx = (b - 157) * 1024 + threadIdx.x * 4;
        const float* src;
        unsigned short* dst;
        if (idx < 110592) { src = qkv_w + idx; dst = wb + idx; }
        else { idx -= 110592; if (idx >= 36864) return; src = proj_w + idx; dst = pwb + idx; }
        float4 v = *(const float4*)src;
        uint2 pk;
        pk.x = pack2bf(v.x, v.y);
        pk.y = pack2bf(v.z, v.w);
        *(uint2*)dst = pk;
        return;
    }
    if (b >= 132) {               // aug table part
        int tau = b - 132;
        int sb = threadIdx.x >> 6, lane = threadIdx.x & 63;
        int g = lane >> 4, qi = lane & 15;
        int s = tau * 64 + sb * 16 + qi;
        int fs = (s * 5243) >> 17;
        int ps = s - fs * 25;
        int fs0 = ((tau * 64) * 5243) >> 17;
        int dfs = fs - fs0;
        unsigned int a[4];
        #pragma unroll
        for (int jj = 0; jj < 4; ++jj) {
            int k0 = g * 8 + 2 * jj, k1 = k0 + 1;
            bool c0 = (k0 < 4) ? (dfs == k0) : (ps == k0 - 4);
            bool c1 = (k1 < 4) ? (dfs == k1) : (ps == k1 - 4);
            a[jj] = (c0 ? 0x3F80u : 0u) | (c1 ? 0x3F800000u : 0u);
        }
        uint4v w = {a[0], a[1], a[2], a[3]};
        *(uint4v*)&augA[((size_t)(tau * 4 + sb) * 64 + lane) * 4] = w;
        return;
    }
    __shared__ float hid[192];
    bool is_t = (b < 127);
    float pos = is_t ? (float)(b - 63) : (float)(b - 127);
    const float* w1 = is_t ? t_w1 : h_w1;
    const float* b1 = is_t ? t_b1 : h_b1;
    const float* w2 = is_t ? t_w2 : h_w2;
    const float* b2 = is_t ? t_b2 : h_b2;
    int t = threadIdx.x;
    if (t < 192) hid[t] = fmaxf(pos * w1[t] + b1[t], 0.0f);
    __syncthreads();
    if (t < 6) {
        float s = b2[t];
        for (int j = 0; j < 192; ++j) s += w2[t * 192 + j] * hid[j];
        s *= SC2F;
        if (is_t) tt[t * 127 + b] = s;
        else      th[t * 5 + (b - 127)] = s;
    }
}

// ---------------------------------------------------------------------------
// Kernel 1: QKV projection, bf16 MFMA GEMM. Weights pre-converted to bf16.
// Q pre-scaled by SC2F.
// ---------------------------------------------------------------------------
__global__ __launch_bounds__(256) void qkv_gemm_kernel(
    const float* __restrict__ x, const unsigned short* __restrict__ wb,
    unsigned short* __restrict__ qout, unsigned short* __restrict__ kout,
    unsigned short* __restrict__ vout)
{
    __shared__ __align__(16) unsigned short alds[64][200];
    __shared__ __align__(16) unsigned short blds[64][72];

    int b = blockIdx.x;
    int bm = b % 200, bn = b / 200;
    int row0 = bm * 64, col0 = bn * 64;
    int tid = threadIdx.x, lane = tid & 63, wv = tid >> 6;
    int g = lane >> 4, qi = lane & 15;

    #pragma unroll
    for (int p = 0; p < 12; ++p) {
        int fid = tid + p * 256;
        int r = fid / 48, c4 = (fid % 48) * 4;
        float4 a4 = *(const float4*)&x[(size_t)(row0 + r) * 192 + c4];
        uint2 pk;
        pk.x = pack2bf(a4.x, a4.y);
        pk.y = pack2bf(a4.z, a4.w);
        *(uint2*)&alds[r][c4] = pk;
    }

    f32x4 acc[4];
    #pragma unroll
    for (int nt = 0; nt < 4; ++nt) acc[nt] = (f32x4){0.f, 0.f, 0.f, 0.f};

    for (int k0 = 0; k0 < 192; k0 += 64) {
        __syncthreads();
        #pragma unroll
        for (int p = 0; p < 2; ++p) {
            int fid = tid + p * 256;
            int j = fid >> 3, kk = (fid & 7) * 8;
            *(uint4*)&blds[j][kk] =
                *(const uint4*)&wb[(size_t)(col0 + j) * 192 + k0 + kk];
        }
        __syncthreads();
        #pragma unroll
        for (int ks = 0; ks < 2; ++ks) {
            bf16x8 af = *(const bf16x8*)&alds[wv * 16 + qi][k0 + ks * 32 + g * 8];
            #pragma unroll
            for (int nt = 0; nt < 4; ++nt) {
                bf16x8 bf = *(const bf16x8*)&blds[nt * 16 + qi][ks * 32 + g * 8];
                acc[nt] = __builtin_amdgcn_mfma_f32_16x16x32_bf16(af, bf, acc[nt], 0, 0, 0);
            }
        }
    }

    #pragma unroll
    for (int nt = 0; nt < 4; ++nt) {
        int col = col0 + nt * 16 + qi;
        int three = col / 192;
        int rem = col - three * 192;
        int h = rem >> 5, c = rem & 31;
        unsigned short* dst = (three == 0) ? qout : ((three == 1) ? kout : vout);
        float scl = (three == 0) ? SC2F : 1.0f;
        #pragma unroll
        for (int r = 0; r < 4; ++r) {
            int row = row0 + wv * 16 + 4 * g + r;
            int n = row / 1600, t = row - n * 1600;
            dst[((size_t)(n * 6 + h) * 1600 + t) * 32 + c] = f2bf(acc[nt][r] * scl);
        }
    }
}

// ---------------------------------------------------------------------------
// Kernel 2: fused attention + relational epilogue (exact R19 revert:
// union-based V pair-pack, if(more)-guarded prefetch, sigma-permuted V^T,
// register-resident P, l via ones-MFMA).
// ---------------------------------------------------------------------------
__global__ __launch_bounds__(256) void attn_kernel(
    const unsigned short* __restrict__ qw, const unsigned short* __restrict__ kw,
    const unsigned short* __restrict__ vw, const float* __restrict__ tt,
    const float* __restrict__ th, const int* __restrict__ hops,
    const unsigned int* __restrict__ augA, const float* __restrict__ outer,
    const float* __restrict__ alpha_p, unsigned short* __restrict__ comb)
{
    __shared__ __align__(16) unsigned short ks[2][64][40];   // K, padded rows
    __shared__ __align__(16) unsigned int vts32[2][32][34];  // V^T, sigma-permuted s-pairs
    __shared__ unsigned int tthi[127], ttlo[127];

    int b = blockIdx.x;
    int serial = (b & 7) * 150 + (b >> 3);   // XCD-contiguous nh chunks
    int nh = serial / 25;
    int qt = serial % 25;
    int h = nh % 6;
    int n = nh / 6;
    int t0 = qt * 64;

    int tid = threadIdx.x;
    int lane = tid & 63, wv = tid >> 6;
    int g = lane >> 4, qi = lane & 15;
    int i = tid & 127;
    bool isK = (wv < 2);

    const unsigned short* qb = qw + (size_t)nh * 51200;
    const unsigned short* kb = kw + (size_t)nh * 51200;
    const unsigned short* vb = vw + (size_t)nh * 51200;

    if (tid < 127) {   // inline ttl hi/lo packing
        float a = tt[h * 127 + tid];
        float bm1 = tt[h * 127 + max(tid - 1, 0)];
        unsigned short ha = f2bf(a), hb = f2bf(bm1);
        tthi[tid] = (unsigned)ha | ((unsigned)hb << 16);
        ttlo[tid] = (unsigned)f2bf(a - bf2f(ha)) |
                    ((unsigned)f2bf(bm1 - bf2f(hb)) << 16);
    }

    int tq = t0 + wv * 16 + qi;
    int ft = (tq * 5243) >> 17;
    int pt = tq - ft * 25;

    bf16x8 qfrag = *(const bf16x8*)&qb[(size_t)tq * 32 + g * 8];

    // static part of B_aug (hop bias, pre-scaled th), hi+lo split
    unsigned int baug_hi[4], baug_lo[4];
    #pragma unroll
    for (int jj = 0; jj < 4; ++jj) {
        int k0 = g * 8 + 2 * jj, k1 = k0 + 1;
        float v0 = 0.f, v1 = 0.f;
        if (k0 >= 4 && k0 < 29) v0 = th[h * 5 + hops[pt * 25 + (k0 - 4)]];
        if (k1 >= 4 && k1 < 29) v1 = th[h * 5 + hops[pt * 25 + (k1 - 4)]];
        unsigned short h0 = f2bf(v0), h1 = f2bf(v1);
        unsigned short l0 = f2bf(v0 - bf2f(h0)), l1 = f2bf(v1 - bf2f(h1));
        baug_hi[jj] = (unsigned)h0 | ((unsigned)h1 << 16);
        baug_lo[jj] = (unsigned)l0 | ((unsigned)l1 << 16);
    }

    f32x4 O0 = {0.f, 0.f, 0.f, 0.f}, O1 = {0.f, 0.f, 0.f, 0.f};
    f32x4 Lacc = {0.f, 0.f, 0.f, 0.f};
    uint4v onesu = {0x3F803F80u, 0x3F803F80u, 0x3F803F80u, 0x3F803F80u};
    bf16x8 onesf = __builtin_bit_cast(bf16x8, onesu);

    const uint4v* augp = (const uint4v*)augA;

    // V staging: sigma-permuted column index (bijective in [0,32))
    int vp = i >> 2, vc8 = (i & 3) * 8;
    int up = (vp & 16) | ((vp & 6) << 1) | ((vp & 8) >> 2) | (vp & 1);

    // ---- prologue: stage tile 0 into buffer 0 ----
    if (isK) {
        int row = i >> 1, c16 = (i & 1) * 16;
        const unsigned short* src = kb + (size_t)row * 32 + c16;
        uint4 a = *(const uint4*)src;
        uint4 bq = *(const uint4*)(src + 8);
        *(uint4*)&ks[0][row][c16] = a;
        *(uint4*)&ks[0][row][c16 + 8] = bq;
    } else {
        const unsigned short* src = vb + (size_t)(2 * vp) * 32 + vc8;
        union { uint4 u; unsigned short s[8]; } a, bq;
        a.u = *(const uint4*)src;
        bq.u = *(const uint4*)(src + 32);
        #pragma unroll
        for (int j = 0; j < 8; ++j)
            vts32[0][vc8 + j][up] = (unsigned)a.s[j] | ((unsigned)bq.s[j] << 16);
    }
    uint4v augr[4];
    #pragma unroll
    for (int sb = 0; sb < 4; ++sb) augr[sb] = augp[(size_t)sb * 64 + lane];
    __syncthreads();

    for (int tau = 0; tau < 25; ++tau) {
        int cur = tau & 1, nxt = cur ^ 1;
        int s0 = tau * 64;
        bool more = (tau < 24);

        // issue next tile's loads early
        uint4 r0 = {0, 0, 0, 0}, r1 = {0, 0, 0, 0};
        uint4v augn[4];
        if (more) {
            if (isK) {
                int row = i >> 1, c16 = (i & 1) * 16;
                const unsigned short* src = kb + (size_t)(s0 + 64 + row) * 32 + c16;
                r0 = *(const uint4*)src;
                r1 = *(const uint4*)(src + 8);
            } else {
                const unsigned short* src = vb + (size_t)(s0 + 64 + 2 * vp) * 32 + vc8;
                r0 = *(const uint4*)src;
                r1 = *(const uint4*)(src + 32);
            }
            #pragma unroll
            for (int sb = 0; sb < 4; ++sb)
                augn[sb] = augp[(size_t)((tau + 1) * 4 + sb) * 64 + lane];
        }

        int fs0 = (s0 * 5243) >> 17;

        // dynamic ttl slots of B_aug from packed tables (g==0 lanes)
        unsigned int bh0 = baug_hi[0], bh1 = baug_hi[1];
        unsigned int bl0 = baug_lo[0], bl1 = baug_lo[1];
        if (g == 0) {
            int base = ft - fs0 + 63;
            bh0 = tthi[base]; bh1 = tthi[base - 2];
            bl0 = ttlo[base]; bl1 = ttlo[base - 2];
        }
        uint4v bhiu = {bh0, bh1, baug_hi[2], baug_hi[3]};
        uint4v blou = {bl0, bl1, baug_lo[2], baug_lo[3]};
        bf16x8 bhif = __builtin_bit_cast(bf16x8, bhiu);
        bf16x8 blof = __builtin_bit_cast(bf16x8, blou);

        // QK^T + bias via table-driven aug-MFMA
        f32x4 sfr[4];
        #pragma unroll
        for (int sb = 0; sb < 4; ++sb) {
            bf16x8 af = __builtin_bit_cast(bf16x8, augr[sb]);
            bf16x8 kf = *(const bf16x8*)&ks[cur][sb * 16 + qi][g * 8];
            f32x4 cz = {0.f, 0.f, 0.f, 0.f};
            f32x4 cb = __builtin_amdgcn_mfma_f32_16x16x32_bf16(af, blof, cz, 0, 0, 0);
            cb = __builtin_amdgcn_mfma_f32_16x16x32_bf16(af, bhif, cb, 0, 0, 0);
            sfr[sb] = __builtin_amdgcn_mfma_f32_16x16x32_bf16(kf, qfrag, cb, 0, 0, 0);
        }

        // unnormalized softmax: p = 2^sfr; keep packed P in registers
        uint2 pkk[4];
        #pragma unroll
        for (int sb = 0; sb < 4; ++sb) {
            float p0 = __builtin_exp2f(sfr[sb][0]);
            float p1 = __builtin_exp2f(sfr[sb][1]);
            float p2 = __builtin_exp2f(sfr[sb][2]);
            float p3 = __builtin_exp2f(sfr[sb][3]);
            pkk[sb].x = cvt_pk_bf16(p0, p1);
            pkk[sb].y = cvt_pk_bf16(p2, p3);
        }

        // stage-writes for tau+1 BEFORE PV
        if (more) {
            if (isK) {
                int row = i >> 1, c16 = (i & 1) * 16;
                *(uint4*)&ks[nxt][row][c16] = r0;
                *(uint4*)&ks[nxt][row][c16 + 8] = r1;
            } else {
                union { uint4 u; unsigned short s[8]; } a, c;
                a.u = r0; c.u = r1;
                #pragma unroll
                for (int j = 0; j < 8; ++j)
                    vts32[nxt][vc8 + j][up] = (unsigned)a.s[j] | ((unsigned)c.s[j] << 16);
            }
            #pragma unroll
            for (int sb = 0; sb < 4; ++sb) augr[sb] = augn[sb];
        }

        #pragma unroll
        for (int c = 0; c < 2; ++c) {
            uint4v pau = {pkk[2 * c].x, pkk[2 * c].y, pkk[2 * c + 1].x, pkk[2 * c + 1].y};
            bf16x8 paf = __builtin_bit_cast(bf16x8, pau);
            uint2 la = *(const uint2*)&vts32[cur][qi][c * 16 + 4 * g];
            uint2 lb = *(const uint2*)&vts32[cur][qi][c * 16 + 4 * g + 2];
            uint2 ha = *(const uint2*)&vts32[cur][16 + qi][c * 16 + 4 * g];
            uint2 hb = *(const uint2*)&vts32[cur][16 + qi][c * 16 + 4 * g + 2];
            uint4v u0 = {la.x, la.y, lb.x, lb.y};
            uint4v u1 = {ha.x, ha.y, hb.x, hb.y};
            bf16x8 v0f = __builtin_bit_cast(bf16x8, u0);
            bf16x8 v1f = __builtin_bit_cast(bf16x8, u1);
            O0 = __builtin_amdgcn_mfma_f32_16x16x32_bf16(paf, v0f, O0, 0, 0, 0);
            O1 = __builtin_amdgcn_mfma_f32_16x16x32_bf16(paf, v1f, O1, 0, 0, 0);
            Lacc = __builtin_amdgcn_mfma_f32_16x16x32_bf16(paf, onesf, Lacc, 0, 0, 0);
        }

        __syncthreads();
    }

    // ---- fused relational epilogue ----
    // Overlay outer[h] (25x26 f32) + V rows (100x32 bf16) onto dead ks buffer.
    float* olds = (float*)&ks[0][0][0];                       // 2600 B
    unsigned short* vl = (unsigned short*)((char*)&ks[0][0][0] + 2720);
    unsigned int* vl32 = (unsigned int*)vl;
    const unsigned int* vb32 = (const unsigned int*)vb;
    int f_lo = (t0 * 5243) >> 17;

    for (int e = tid; e < 625; e += 256)
        olds[(e / 25) * 26 + (e % 25)] = outer[h * 625 + e];
    for (int w = tid; w < 1600; w += 256) {
        int row = w >> 4, c2 = w & 15;
        int grow = min(f_lo * 25 + row, 1599);
        vl32[row * 16 + c2] = vb32[(size_t)grow * 16 + c2];
    }
    __syncthreads();

    float alpha = alpha_p[0];
    int trow = t0 + wv * 16;
    #pragma unroll
    for (int r = 0; r < 4; ++r) {
        float wr = alpha / Lacc[r];
        int t = trow + 4 * g + r;
        int ftt = (t * 5243) >> 17;
        int ptt = t - ftt * 25;
        int vbr = (ftt - f_lo) * 25;
        float rel0 = 0.f, rel1 = 0.f;
        #pragma unroll
        for (int q = 0; q < 25; ++q) {
            float ow = olds[ptt * 26 + q];
            rel0 += ow * bf2f(vl[(vbr + q) * 32 + qi]);
            rel1 += ow * bf2f(vl[(vbr + q) * 32 + 16 + qi]);
        }
        size_t cb = ((size_t)(n * 1600 + t)) * 192 + h * 32;
        comb[cb + qi] = f2bf(O0[r] * wr + rel0);
        comb[cb + 16 + qi] = f2bf(O1[r] * wr + rel1);
    }
}

// ---------------------------------------------------------------------------
// Kernel 3: final projection, bf16 MFMA GEMM. Weights pre-converted to bf16.
// ---------------------------------------------------------------------------
__global__ __launch_bounds__(256) void proj_gemm_kernel(
    const unsigned short* __restrict__ comb, const unsigned short* __restrict__ pwb,
    const float* __restrict__ pb, float* __restrict__ out)
{
    __shared__ __align__(16) unsigned short alds[64][200];
    __shared__ __align__(16) unsigned short blds[64][72];

    int b = blockIdx.x;
    int bm = b % 200, bn = b / 200;
    int row0 = bm * 64, col0 = bn * 64;
    int tid = threadIdx.x, lane = tid & 63, wv = tid >> 6;
    int g = lane >> 4, qi = lane & 15;

    #pragma unroll
    for (int p = 0; p < 6; ++p) {
        int fid = tid + p * 256;
        int r = fid / 24, c8 = (fid % 24) * 8;
        *(uint4*)&alds[r][c8] = *(const uint4*)&comb[(size_t)(row0 + r) * 192 + c8];
    }

    f32x4 acc[4];
    #pragma unroll
    for (int nt = 0; nt < 4; ++nt) acc[nt] = (f32x4){0.f, 0.f, 0.f, 0.f};

    for (int k0 = 0; k0 < 192; k0 += 64) {
        __syncthreads();
        #pragma unroll
        for (int p = 0; p < 2; ++p) {
            int fid = tid + p * 256;
            int j = fid >> 3, kk = (fid & 7) * 8;
            *(uint4*)&blds[j][kk] =
                *(const uint4*)&pwb[(size_t)(col0 + j) * 192 + k0 + kk];
        }
        __syncthreads();
        #pragma unroll
        for (int ks = 0; ks < 2; ++ks) {
            bf16x8 af = *(const bf16x8*)&alds[wv * 16 + qi][k0 + ks * 32 + g * 8];
            #pragma unroll
            for (int nt = 0; nt < 4; ++nt) {
                bf16x8 bf = *(const bf16x8*)&blds[nt * 16 + qi][ks * 32 + g * 8];
                acc[nt] = __builtin_amdgcn_mfma_f32_16x16x32_bf16(af, bf, acc[nt], 0, 0, 0);
            }
        }
    }

    #pragma unroll
    for (int nt = 0; nt < 4; ++nt) {
        int col = col0 + nt * 16 + qi;
        float bias = pb[col];
        #pragma unroll
        for (int r = 0; r < 4; ++r) {
            int row = row0 + wv * 16 + 4 * g + r;
            out[(size_t)row * 192 + col] = acc[nt][r] + bias;
        }
    }
}

// ---------------------------------------------------------------------------
extern "C" void kernel_launch(void* const* d_in, const int* in_sizes, int n_in,
                              void* d_out, int out_size, void* d_ws, size_t ws_size,
                              hipStream_t stream)
{
    const float* x      = (const float*)d_in[0];
    const float* qkv_w  = (const float*)d_in[1];
    const float* proj_w = (const float*)d_in[2];
    const float* proj_b = (const float*)d_in[3];
    const float* t_w1   = (const float*)d_in[4];
    const float* t_b1   = (const float*)d_in[5];
    const float* t_w2   = (const float*)d_in[6];
    const float* t_b2   = (const float*)d_in[7];
    const float* h_w1   = (const float*)d_in[8];
    const float* h_b1   = (const float*)d_in[9];
    const float* h_w2   = (const float*)d_in[10];
    const float* h_b2   = (const float*)d_in[11];
    const float* outer  = (const float*)d_in[12];
    const float* alpha  = (const float*)d_in[13];
    const int*   hops   = (const int*)d_in[14];
    float* out = (float*)d_out;

    char* w8 = (char*)d_ws;
    float* tt = (float*)w8;                                  // 762 f @ 0
    float* th = (float*)(w8 + 3072);                         // 30 f
    unsigned int* augA = (unsigned int*)(w8 + 10240);        // 102400 B
    unsigned short* wb  = (unsigned short*)(w8 + 112640);    // 221184 B
    unsigned short* pwb = (unsigned short*)(w8 + 333824);    // 73728 B
    unsigned short* qb = (unsigned short*)(w8 + 409600);
    unsigned short* kb = qb + 2457600;
    unsigned short* vb = kb + 2457600;
    unsigned short* comb = (unsigned short*)(w8 + 409600 + 3 * 4915200);

    prep_kernel<<<301, 256, 0, stream>>>(t_w1, t_b1, t_w2, t_b2,
                                         h_w1, h_b1, h_w2, h_b2,
                                         qkv_w, proj_w, tt, th, augA, wb, pwb);
    qkv_gemm_kernel<<<1800, 256, 0, stream>>>(x, wb, qb, kb, vb);
    attn_kernel<<<1200, 256, 0, stream>>>(qb, kb, vb, tt, th, hops, augA,
                                          outer, alpha, comb);
    proj_gemm_kernel<<<600, 256, 0, stream>>>(comb, pwb, proj_b, out);
}

// Round 23
// 92.037 us; speedup vs baseline: 1.2772x; 1.0070x over previous
//
#include <hip/hip_runtime.h>
#include <math.h>

#define N_ 8
#define F_ 64
#define P_ 25
#define H_ 6
#define D_ 192
#define HD_ 32
#define T_ 1600
#define SC2F 0.25503486f   // SCALE * log2(e)

typedef short bf16x8 __attribute__((ext_vector_type(8)));
typedef float f32x4 __attribute__((ext_vector_type(4)));
typedef unsigned int uint4v __attribute__((ext_vector_type(4)));

__device__ __forceinline__ unsigned short f2bf(float f) {
    unsigned int u = __float_as_uint(f);
    u += 0x7fffu + ((u >> 16) & 1u);
    return (unsigned short)(u >> 16);
}
__device__ __forceinline__ float bf2f(unsigned short s) {
    return __uint_as_float(((unsigned int)s) << 16);
}
__device__ __forceinline__ unsigned int pack2bf(float lo, float hi) {
    return (unsigned int)f2bf(lo) | ((unsigned int)f2bf(hi) << 16);
}
__device__ __forceinline__ unsigned int cvt_pk_bf16(float lo, float hi) {
    unsigned int r;
    asm("v_cvt_pk_bf16_f32 %0, %1, %2" : "=v"(r) : "v"(lo), "v"(hi));
    return r;
}

// ---------------------------------------------------------------------------
// Kernel 0 (merged): blocks 0-131 = bias MLP tables (pre-scaled by SC2F);
// blocks 132-156 = onehot A-fragment table; blocks 157-300 = bf16 weight
// conversion (qkv_w then proj_w).
// ---------------------------------------------------------------------------
__global__ __launch_bounds__(256) void prep_kernel(
    const float* __restrict__ t_w1, const float* __restrict__ t_b1,
    const float* __restrict__ t_w2, const float* __restrict__ t_b2,
    const float* __restrict__ h_w1, const float* __restrict__ h_b1,
    const float* __restrict__ h_w2, const float* __restrict__ h_b2,
    const float* __restrict__ qkv_w, const float* __restrict__ proj_w,
    float* __restrict__ tt, float* __restrict__ th,
    unsigned int* __restrict__ augA,
    unsigned short* __restrict__ wb, unsigned short* __restrict__ pwb)
{
    int b = blockIdx.x;
    if (b >= 157) {               // weight conversion part
        int idx = (b - 157) * 1024 + threadIdx.x * 4;
        const float* src;
        unsigned short* dst;
        if (idx < 110592) { src = qkv_w + idx; dst = wb + idx; }
        else { idx -= 110592; if (idx >= 36864) return; src = proj_w + idx; dst = pwb + idx; }
        float4 v = *(const float4*)src;
        uint2 pk;
        pk.x = pack2bf(v.x, v.y);
        pk.y = pack2bf(v.z, v.w);
        *(uint2*)dst = pk;
        return;
    }
    if (b >= 132) {               // aug table part
        int tau = b - 132;
        int sb = threadIdx.x >> 6, lane = threadIdx.x & 63;
        int g = lane >> 4, qi = lane & 15;
        int s = tau * 64 + sb * 16 + qi;
        int fs = (s * 5243) >> 17;
        int ps = s - fs * 25;
        int fs0 = ((tau * 64) * 5243) >> 17;
        int dfs = fs - fs0;
        unsigned int a[4];
        #pragma unroll
        for (int jj = 0; jj < 4; ++jj) {
            int k0 = g * 8 + 2 * jj, k1 = k0 + 1;
            bool c0 = (k0 < 4) ? (dfs == k0) : (ps == k0 - 4);
            bool c1 = (k1 < 4) ? (dfs == k1) : (ps == k1 - 4);
            a[jj] = (c0 ? 0x3F80u : 0u) | (c1 ? 0x3F800000u : 0u);
        }
        uint4v w = {a[0], a[1], a[2], a[3]};
        *(uint4v*)&augA[((size_t)(tau * 4 + sb) * 64 + lane) * 4] = w;
        return;
    }
    __shared__ float hid[192];
    bool is_t = (b < 127);
    float pos = is_t ? (float)(b - 63) : (float)(b - 127);
    const float* w1 = is_t ? t_w1 : h_w1;
    const float* b1 = is_t ? t_b1 : h_b1;
    const float* w2 = is_t ? t_w2 : h_w2;
    const float* b2 = is_t ? t_b2 : h_b2;
    int t = threadIdx.x;
    if (t < 192) hid[t] = fmaxf(pos * w1[t] + b1[t], 0.0f);
    __syncthreads();
    if (t < 6) {
        float s = b2[t];
        for (int j = 0; j < 192; ++j) s += w2[t * 192 + j] * hid[j];
        s *= SC2F;
        if (is_t) tt[t * 127 + b] = s;
        else      th[t * 5 + (b - 127)] = s;
    }
}

// ---------------------------------------------------------------------------
// Kernel 1: QKV projection, bf16 MFMA GEMM. Weights pre-converted to bf16.
// Q pre-scaled by SC2F.
// ---------------------------------------------------------------------------
__global__ __launch_bounds__(256) void qkv_gemm_kernel(
    const float* __restrict__ x, const unsigned short* __restrict__ wb,
    unsigned short* __restrict__ qout, unsigned short* __restrict__ kout,
    unsigned short* __restrict__ vout)
{
    __shared__ __align__(16) unsigned short alds[64][200];
    __shared__ __align__(16) unsigned short blds[64][72];

    int b = blockIdx.x;
    int bm = b % 200, bn = b / 200;
    int row0 = bm * 64, col0 = bn * 64;
    int tid = threadIdx.x, lane = tid & 63, wv = tid >> 6;
    int g = lane >> 4, qi = lane & 15;

    #pragma unroll
    for (int p = 0; p < 12; ++p) {
        int fid = tid + p * 256;
        int r = fid / 48, c4 = (fid % 48) * 4;
        float4 a4 = *(const float4*)&x[(size_t)(row0 + r) * 192 + c4];
        uint2 pk;
        pk.x = pack2bf(a4.x, a4.y);
        pk.y = pack2bf(a4.z, a4.w);
        *(uint2*)&alds[r][c4] = pk;
    }

    f32x4 acc[4];
    #pragma unroll
    for (int nt = 0; nt < 4; ++nt) acc[nt] = (f32x4){0.f, 0.f, 0.f, 0.f};

    for (int k0 = 0; k0 < 192; k0 += 64) {
        __syncthreads();
        #pragma unroll
        for (int p = 0; p < 2; ++p) {
            int fid = tid + p * 256;
            int j = fid >> 3, kk = (fid & 7) * 8;
            *(uint4*)&blds[j][kk] =
                *(const uint4*)&wb[(size_t)(col0 + j) * 192 + k0 + kk];
        }
        __syncthreads();
        #pragma unroll
        for (int ks = 0; ks < 2; ++ks) {
            bf16x8 af = *(const bf16x8*)&alds[wv * 16 + qi][k0 + ks * 32 + g * 8];
            #pragma unroll
            for (int nt = 0; nt < 4; ++nt) {
                bf16x8 bf = *(const bf16x8*)&blds[nt * 16 + qi][ks * 32 + g * 8];
                acc[nt] = __builtin_amdgcn_mfma_f32_16x16x32_bf16(af, bf, acc[nt], 0, 0, 0);
            }
        }
    }

    #pragma unroll
    for (int nt = 0; nt < 4; ++nt) {
        int col = col0 + nt * 16 + qi;
        int three = col / 192;
        int rem = col - three * 192;
        int h = rem >> 5, c = rem & 31;
        unsigned short* dst = (three == 0) ? qout : ((three == 1) ? kout : vout);
        float scl = (three == 0) ? SC2F : 1.0f;
        #pragma unroll
        for (int r = 0; r < 4; ++r) {
            int row = row0 + wv * 16 + 4 * g + r;
            int n = row / 1600, t = row - n * 1600;
            dst[((size_t)(n * 6 + h) * 1600 + t) * 32 + c] = f2bf(acc[nt][r] * scl);
        }
    }
}

// ---------------------------------------------------------------------------
// Kernel 2: fused attention + relational epilogue (R22 structure, tau loop
// unrolled 2x to eliminate aug register copies and buffer-flip overhead).
// ---------------------------------------------------------------------------
__global__ __launch_bounds__(256) void attn_kernel(
    const unsigned short* __restrict__ qw, const unsigned short* __restrict__ kw,
    const unsigned short* __restrict__ vw, const float* __restrict__ tt,
    const float* __restrict__ th, const int* __restrict__ hops,
    const unsigned int* __restrict__ augA, const float* __restrict__ outer,
    const float* __restrict__ alpha_p, unsigned short* __restrict__ comb)
{
    __shared__ __align__(16) unsigned short ks[2][64][40];   // K, padded rows
    __shared__ __align__(16) unsigned int vts32[2][32][34];  // V^T, sigma-permuted s-pairs
    __shared__ unsigned int tthi[127], ttlo[127];

    int b = blockIdx.x;
    int serial = (b & 7) * 150 + (b >> 3);   // XCD-contiguous nh chunks
    int nh = serial / 25;
    int qt = serial % 25;
    int h = nh % 6;
    int n = nh / 6;
    int t0 = qt * 64;

    int tid = threadIdx.x;
    int lane = tid & 63, wv = tid >> 6;
    int g = lane >> 4, qi = lane & 15;
    int i = tid & 127;
    bool isK = (wv < 2);

    const unsigned short* qb = qw + (size_t)nh * 51200;
    const unsigned short* kb = kw + (size_t)nh * 51200;
    const unsigned short* vb = vw + (size_t)nh * 51200;

    if (tid < 127) {   // inline ttl hi/lo packing
        float a = tt[h * 127 + tid];
        float bm1 = tt[h * 127 + max(tid - 1, 0)];
        unsigned short ha = f2bf(a), hb = f2bf(bm1);
        tthi[tid] = (unsigned)ha | ((unsigned)hb << 16);
        ttlo[tid] = (unsigned)f2bf(a - bf2f(ha)) |
                    ((unsigned)f2bf(bm1 - bf2f(hb)) << 16);
    }

    int tq = t0 + wv * 16 + qi;
    int ft = (tq * 5243) >> 17;
    int pt = tq - ft * 25;

    bf16x8 qfrag = *(const bf16x8*)&qb[(size_t)tq * 32 + g * 8];

    // static part of B_aug (hop bias, pre-scaled th), hi+lo split
    unsigned int baug_hi[4], baug_lo[4];
    #pragma unroll
    for (int jj = 0; jj < 4; ++jj) {
        int k0 = g * 8 + 2 * jj, k1 = k0 + 1;
        float v0 = 0.f, v1 = 0.f;
        if (k0 >= 4 && k0 < 29) v0 = th[h * 5 + hops[pt * 25 + (k0 - 4)]];
        if (k1 >= 4 && k1 < 29) v1 = th[h * 5 + hops[pt * 25 + (k1 - 4)]];
        unsigned short h0 = f2bf(v0), h1 = f2bf(v1);
        unsigned short l0 = f2bf(v0 - bf2f(h0)), l1 = f2bf(v1 - bf2f(h1));
        baug_hi[jj] = (unsigned)h0 | ((unsigned)h1 << 16);
        baug_lo[jj] = (unsigned)l0 | ((unsigned)l1 << 16);
    }

    f32x4 O0 = {0.f, 0.f, 0.f, 0.f}, O1 = {0.f, 0.f, 0.f, 0.f};
    f32x4 Lacc = {0.f, 0.f, 0.f, 0.f};
    uint4v onesu = {0x3F803F80u, 0x3F803F80u, 0x3F803F80u, 0x3F803F80u};
    bf16x8 onesf = __builtin_bit_cast(bf16x8, onesu);

    const uint4v* augp = (const uint4v*)augA;

    // V staging: sigma-permuted column index (bijective in [0,32))
    int vp = i >> 2, vc8 = (i & 3) * 8;
    int up = (vp & 16) | ((vp & 6) << 1) | ((vp & 8) >> 2) | (vp & 1);

    // ---- prologue: stage tile 0 into buffer 0 ----
    if (isK) {
        int row = i >> 1, c16 = (i & 1) * 16;
        const unsigned short* src = kb + (size_t)row * 32 + c16;
        uint4 a = *(const uint4*)src;
        uint4 bq = *(const uint4*)(src + 8);
        *(uint4*)&ks[0][row][c16] = a;
        *(uint4*)&ks[0][row][c16 + 8] = bq;
    } else {
        const unsigned short* src = vb + (size_t)(2 * vp) * 32 + vc8;
        union { uint4 u; unsigned short s[8]; } a, bq;
        a.u = *(const uint4*)src;
        bq.u = *(const uint4*)(src + 32);
        #pragma unroll
        for (int j = 0; j < 8; ++j)
            vts32[0][vc8 + j][up] = (unsigned)a.s[j] | ((unsigned)bq.s[j] << 16);
    }
    uint4v augr[4];
    #pragma unroll
    for (int sb = 0; sb < 4; ++sb) augr[sb] = augp[(size_t)sb * 64 + lane];
    __syncthreads();

    #pragma unroll 2
    for (int tau = 0; tau < 25; ++tau) {
        int cur = tau & 1, nxt = cur ^ 1;
        int s0 = tau * 64;
        bool more = (tau < 24);

        // issue next tile's loads early
        uint4 r0 = {0, 0, 0, 0}, r1 = {0, 0, 0, 0};
        uint4v augn[4];
        if (more) {
            if (isK) {
                int row = i >> 1, c16 = (i & 1) * 16;
                const unsigned short* src = kb + (size_t)(s0 + 64 + row) * 32 + c16;
                r0 = *(const uint4*)src;
                r1 = *(const uint4*)(src + 8);
            } else {
                const unsigned short* src = vb + (size_t)(s0 + 64 + 2 * vp) * 32 + vc8;
                r0 = *(const uint4*)src;
                r1 = *(const uint4*)(src + 32);
            }
            #pragma unroll
            for (int sb = 0; sb < 4; ++sb)
                augn[sb] = augp[(size_t)((tau + 1) * 4 + sb) * 64 + lane];
        }

        int fs0 = (s0 * 5243) >> 17;

        // dynamic ttl slots of B_aug from packed tables (g==0 lanes)
        unsigned int bh0 = baug_hi[0], bh1 = baug_hi[1];
        unsigned int bl0 = baug_lo[0], bl1 = baug_lo[1];
        if (g == 0) {
            int base = ft - fs0 + 63;
            bh0 = tthi[base]; bh1 = tthi[base - 2];
            bl0 = ttlo[base]; bl1 = ttlo[base - 2];
        }
        uint4v bhiu = {bh0, bh1, baug_hi[2], baug_hi[3]};
        uint4v blou = {bl0, bl1, baug_lo[2], baug_lo[3]};
        bf16x8 bhif = __builtin_bit_cast(bf16x8, bhiu);
        bf16x8 blof = __builtin_bit_cast(bf16x8, blou);

        // QK^T + bias via table-driven aug-MFMA
        f32x4 sfr[4];
        #pragma unroll
        for (int sb = 0; sb < 4; ++sb) {
            bf16x8 af = __builtin_bit_cast(bf16x8, augr[sb]);
            bf16x8 kf = *(const bf16x8*)&ks[cur][sb * 16 + qi][g * 8];
            f32x4 cz = {0.f, 0.f, 0.f, 0.f};
            f32x4 cb = __builtin_amdgcn_mfma_f32_16x16x32_bf16(af, blof, cz, 0, 0, 0);
            cb = __builtin_amdgcn_mfma_f32_16x16x32_bf16(af, bhif, cb, 0, 0, 0);
            sfr[sb] = __builtin_amdgcn_mfma_f32_16x16x32_bf16(kf, qfrag, cb, 0, 0, 0);
        }

        // unnormalized softmax: p = 2^sfr; keep packed P in registers
        uint2 pkk[4];
        #pragma unroll
        for (int sb = 0; sb < 4; ++sb) {
            float p0 = __builtin_exp2f(sfr[sb][0]);
            float p1 = __builtin_exp2f(sfr[sb][1]);
            float p2 = __builtin_exp2f(sfr[sb][2]);
            float p3 = __builtin_exp2f(sfr[sb][3]);
            pkk[sb].x = cvt_pk_bf16(p0, p1);
            pkk[sb].y = cvt_pk_bf16(p2, p3);
        }

        // stage-writes for tau+1 BEFORE PV
        if (more) {
            if (isK) {
                int row = i >> 1, c16 = (i & 1) * 16;
                *(uint4*)&ks[nxt][row][c16] = r0;
                *(uint4*)&ks[nxt][row][c16 + 8] = r1;
            } else {
                union { uint4 u; unsigned short s[8]; } a, c;
                a.u = r0; c.u = r1;
                #pragma unroll
                for (int j = 0; j < 8; ++j)
                    vts32[nxt][vc8 + j][up] = (unsigned)a.s[j] | ((unsigned)c.s[j] << 16);
            }
            #pragma unroll
            for (int sb = 0; sb < 4; ++sb) augr[sb] = augn[sb];
        }

        #pragma unroll
        for (int c = 0; c < 2; ++c) {
            uint4v pau = {pkk[2 * c].x, pkk[2 * c].y, pkk[2 * c + 1].x, pkk[2 * c + 1].y};
            bf16x8 paf = __builtin_bit_cast(bf16x8, pau);
            uint2 la = *(const uint2*)&vts32[cur][qi][c * 16 + 4 * g];
            uint2 lb = *(const uint2*)&vts32[cur][qi][c * 16 + 4 * g + 2];
            uint2 ha = *(const uint2*)&vts32[cur][16 + qi][c * 16 + 4 * g];
            uint2 hb = *(const uint2*)&vts32[cur][16 + qi][c * 16 + 4 * g + 2];
            uint4v u0 = {la.x, la.y, lb.x, lb.y};
            uint4v u1 = {ha.x, ha.y, hb.x, hb.y};
            bf16x8 v0f = __builtin_bit_cast(bf16x8, u0);
            bf16x8 v1f = __builtin_bit_cast(bf16x8, u1);
            O0 = __builtin_amdgcn_mfma_f32_16x16x32_bf16(paf, v0f, O0, 0, 0, 0);
            O1 = __builtin_amdgcn_mfma_f32_16x16x32_bf16(paf, v1f, O1, 0, 0, 0);
            Lacc = __builtin_amdgcn_mfma_f32_16x16x32_bf16(paf, onesf, Lacc, 0, 0, 0);
        }

        __syncthreads();
    }

    // ---- fused relational epilogue ----
    // Overlay outer[h] (25x26 f32) + V rows (100x32 bf16) onto dead ks buffer.
    float* olds = (float*)&ks[0][0][0];                       // 2600 B
    unsigned short* vl = (unsigned short*)((char*)&ks[0][0][0] + 2720);
    unsigned int* vl32 = (unsigned int*)vl;
    const unsigned int* vb32 = (const unsigned int*)vb;
    int f_lo = (t0 * 5243) >> 17;

    for (int e = tid; e < 625; e += 256)
        olds[(e / 25) * 26 + (e % 25)] = outer[h * 625 + e];
    for (int w = tid; w < 1600; w += 256) {
        int row = w >> 4, c2 = w & 15;
        int grow = min(f_lo * 25 + row, 1599);
        vl32[row * 16 + c2] = vb32[(size_t)grow * 16 + c2];
    }
    __syncthreads();

    float alpha = alpha_p[0];
    int trow = t0 + wv * 16;
    #pragma unroll
    for (int r = 0; r < 4; ++r) {
        float wr = alpha / Lacc[r];
        int t = trow + 4 * g + r;
        int ftt = (t * 5243) >> 17;
        int ptt = t - ftt * 25;
        int vbr = (ftt - f_lo) * 25;
        float rel0 = 0.f, rel1 = 0.f;
        #pragma unroll
        for (int q = 0; q < 25; ++q) {
            float ow = olds[ptt * 26 + q];
            rel0 += ow * bf2f(vl[(vbr + q) * 32 + qi]);
            rel1 += ow * bf2f(vl[(vbr + q) * 32 + 16 + qi]);
        }
        size_t cb = ((size_t)(n * 1600 + t)) * 192 + h * 32;
        comb[cb + qi] = f2bf(O0[r] * wr + rel0);
        comb[cb + 16 + qi] = f2bf(O1[r] * wr + rel1);
    }
}

// ---------------------------------------------------------------------------
// Kernel 3: final projection, bf16 MFMA GEMM. Weights pre-converted to bf16.
// ---------------------------------------------------------------------------
__global__ __launch_bounds__(256) void proj_gemm_kernel(
    const unsigned short* __restrict__ comb, const unsigned short* __restrict__ pwb,
    const float* __restrict__ pb, float* __restrict__ out)
{
    __shared__ __align__(16) unsigned short alds[64][200];
    __shared__ __align__(16) unsigned short blds[64][72];

    int b = blockIdx.x;
    int bm = b % 200, bn = b / 200;
    int row0 = bm * 64, col0 = bn * 64;
    int tid = threadIdx.x, lane = tid & 63, wv = tid >> 6;
    int g = lane >> 4, qi = lane & 15;

    #pragma unroll
    for (int p = 0; p < 6; ++p) {
        int fid = tid + p * 256;
        int r = fid / 24, c8 = (fid % 24) * 8;
        *(uint4*)&alds[r][c8] = *(const uint4*)&comb[(size_t)(row0 + r) * 192 + c8];
    }

    f32x4 acc[4];
    #pragma unroll
    for (int nt = 0; nt < 4; ++nt) acc[nt] = (f32x4){0.f, 0.f, 0.f, 0.f};

    for (int k0 = 0; k0 < 192; k0 += 64) {
        __syncthreads();
        #pragma unroll
        for (int p = 0; p < 2; ++p) {
            int fid = tid + p * 256;
            int j = fid >> 3, kk = (fid & 7) * 8;
            *(uint4*)&blds[j][kk] =
                *(const uint4*)&pwb[(size_t)(col0 + j) * 192 + k0 + kk];
        }
        __syncthreads();
        #pragma unroll
        for (int ks = 0; ks < 2; ++ks) {
            bf16x8 af = *(const bf16x8*)&alds[wv * 16 + qi][k0 + ks * 32 + g * 8];
            #pragma unroll
            for (int nt = 0; nt < 4; ++nt) {
                bf16x8 bf = *(const bf16x8*)&blds[nt * 16 + qi][ks * 32 + g * 8];
                acc[nt] = __builtin_amdgcn_mfma_f32_16x16x32_bf16(af, bf, acc[nt], 0, 0, 0);
            }
        }
    }

    #pragma unroll
    for (int nt = 0; nt < 4; ++nt) {
        int col = col0 + nt * 16 + qi;
        float bias = pb[col];
        #pragma unroll
        for (int r = 0; r < 4; ++r) {
            int row = row0 + wv * 16 + 4 * g + r;
            out[(size_t)row * 192 + col] = acc[nt][r] + bias;
        }
    }
}

// ---------------------------------------------------------------------------
extern "C" void kernel_launch(void* const* d_in, const int* in_sizes, int n_in,
                              void* d_out, int out_size, void* d_ws, size_t ws_size,
                              hipStream_t stream)
{
    const float* x      = (const float*)d_in[0];
    const float* qkv_w  = (const float*)d_in[1];
    const float* proj_w = (const float*)d_in[2];
    const float* proj_b = (const float*)d_in[3];
    const float* t_w1   = (const float*)d_in[4];
    const float* t_b1   = (const float*)d_in[5];
    const float* t_w2   = (const float*)d_in[6];
    const float* t_b2   = (const float*)d_in[7];
    const float* h_w1   = (const float*)d_in[8];
    const float* h_b1   = (const float*)d_in[9];
    const float* h_w2   = (const float*)d_in[10];
    const float* h_b2   = (const float*)d_in[11];
    const float* outer  = (const float*)d_in[12];
    const float* alpha  = (const float*)d_in[13];
    const int*   hops   = (const int*)d_in[14];
    float* out = (float*)d_out;

    char* w8 = (char*)d_ws;
    float* tt = (float*)w8;                                  // 762 f @ 0
    float* th = (float*)(w8 + 3072);                         // 30 f
    unsigned int* augA = (unsigned int*)(w8 + 10240);        // 102400 B
    unsigned short* wb  = (unsigned short*)(w8 + 112640);    // 221184 B
    unsigned short* pwb = (unsigned short*)(w8 + 333824);    // 73728 B
    unsigned short* qb = (unsigned short*)(w8 + 409600);
    unsigned short* kb = qb + 2457600;
    unsigned short* vb = kb + 2457600;
    unsigned short* comb = (unsigned short*)(w8 + 409600 + 3 * 4915200);

    prep_kernel<<<301, 256, 0, stream>>>(t_w1, t_b1, t_w2, t_b2,
                                         h_w1, h_b1, h_w2, h_b2,
                                         qkv_w, proj_w, tt, th, augA, wb, pwb);
    qkv_gemm_kernel<<<1800, 256, 0, stream>>>(x, wb, qb, kb, vb);
    attn_kernel<<<1200, 256, 0, stream>>>(qb, kb, vb, tt, th, hops, augA,
                                          outer, alpha, comb);
    proj_gemm_kernel<<<600, 256, 0, stream>>>(comb, pwb, proj_b, out);
}

// Round 24
// 90.903 us; speedup vs baseline: 1.2932x; 1.0125x over previous
//
#include <hip/hip_runtime.h>
#include <math.h>

#define N_ 8
#define F_ 64
#define P_ 25
#define H_ 6
#define D_ 192
#define HD_ 32
#define T_ 1600
#define SC2F 0.25503486f   // SCALE * log2(e)

typedef short bf16x8 __attribute__((ext_vector_type(8)));
typedef float f32x4 __attribute__((ext_vector_type(4)));
typedef unsigned int uint4v __attribute__((ext_vector_type(4)));

__device__ __forceinline__ unsigned short f2bf(float f) {
    unsigned int u = __float_as_uint(f);
    u += 0x7fffu + ((u >> 16) & 1u);
    return (unsigned short)(u >> 16);
}
__device__ __forceinline__ float bf2f(unsigned short s) {
    return __uint_as_float(((unsigned int)s) << 16);
}
__device__ __forceinline__ unsigned int pack2bf(float lo, float hi) {
    return (unsigned int)f2bf(lo) | ((unsigned int)f2bf(hi) << 16);
}
__device__ __forceinline__ unsigned int cvt_pk_bf16(float lo, float hi) {
    unsigned int r;
    asm("v_cvt_pk_bf16_f32 %0, %1, %2" : "=v"(r) : "v"(lo), "v"(hi));
    return r;
}

// ---------------------------------------------------------------------------
// Kernel 0 (merged): blocks 0-131 = bias MLP tables (pre-scaled by SC2F);
// blocks 132-156 = onehot A-fragment table; blocks 157-300 = bf16 weight
// conversion (qkv_w then proj_w).
// ---------------------------------------------------------------------------
__global__ __launch_bounds__(256) void prep_kernel(
    const float* __restrict__ t_w1, const float* __restrict__ t_b1,
    const float* __restrict__ t_w2, const float* __restrict__ t_b2,
    const float* __restrict__ h_w1, const float* __restrict__ h_b1,
    const float* __restrict__ h_w2, const float* __restrict__ h_b2,
    const float* __restrict__ qkv_w, const float* __restrict__ proj_w,
    float* __restrict__ tt, float* __restrict__ th,
    unsigned int* __restrict__ augA,
    unsigned short* __restrict__ wb, unsigned short* __restrict__ pwb)
{
    int b = blockIdx.x;
    if (b >= 157) {               // weight conversion part
        int idx = (b - 157) * 1024 + threadIdx.x * 4;
        const float* src;
        unsigned short* dst;
        if (idx < 110592) { src = qkv_w + idx; dst = wb + idx; }
        else { idx -= 110592; if (idx >= 36864) return; src = proj_w + idx; dst = pwb + idx; }
        float4 v = *(const float4*)src;
        uint2 pk;
        pk.x = pack2bf(v.x, v.y);
        pk.y = pack2bf(v.z, v.w);
        *(uint2*)dst = pk;
        return;
    }
    if (b >= 132) {               // aug table part
        int tau = b - 132;
        int sb = threadIdx.x >> 6, lane = threadIdx.x & 63;
        int g = lane >> 4, qi = lane & 15;
        int s = tau * 64 + sb * 16 + qi;
        int fs = (s * 5243) >> 17;
        int ps = s - fs * 25;
        int fs0 = ((tau * 64) * 5243) >> 17;
        int dfs = fs - fs0;
        unsigned int a[4];
        #pragma unroll
        for (int jj = 0; jj < 4; ++jj) {
            int k0 = g * 8 + 2 * jj, k1 = k0 + 1;
            bool c0 = (k0 < 4) ? (dfs == k0) : (ps == k0 - 4);
            bool c1 = (k1 < 4) ? (dfs == k1) : (ps == k1 - 4);
            a[jj] = (c0 ? 0x3F80u : 0u) | (c1 ? 0x3F800000u : 0u);
        }
        uint4v w = {a[0], a[1], a[2], a[3]};
        *(uint4v*)&augA[((size_t)(tau * 4 + sb) * 64 + lane) * 4] = w;
        return;
    }
    __shared__ float hid[192];
    bool is_t = (b < 127);
    float pos = is_t ? (float)(b - 63) : (float)(b - 127);
    const float* w1 = is_t ? t_w1 : h_w1;
    const float* b1 = is_t ? t_b1 : h_b1;
    const float* w2 = is_t ? t_w2 : h_w2;
    const float* b2 = is_t ? t_b2 : h_b2;
    int t = threadIdx.x;
    if (t < 192) hid[t] = fmaxf(pos * w1[t] + b1[t], 0.0f);
    __syncthreads();
    if (t < 6) {
        float s = b2[t];
        for (int j = 0; j < 192; ++j) s += w2[t * 192 + j] * hid[j];
        s *= SC2F;
        if (is_t) tt[t * 127 + b] = s;
        else      th[t * 5 + (b - 127)] = s;
    }
}

// ---------------------------------------------------------------------------
// Kernel 1: QKV projection, bf16 MFMA GEMM. Weights pre-converted to bf16.
// Q pre-scaled by SC2F.
// ---------------------------------------------------------------------------
__global__ __launch_bounds__(256) void qkv_gemm_kernel(
    const float* __restrict__ x, const unsigned short* __restrict__ wb,
    unsigned short* __restrict__ qout, unsigned short* __restrict__ kout,
    unsigned short* __restrict__ vout)
{
    __shared__ __align__(16) unsigned short alds[64][200];
    __shared__ __align__(16) unsigned short blds[64][72];

    int b = blockIdx.x;
    int bm = b % 200, bn = b / 200;
    int row0 = bm * 64, col0 = bn * 64;
    int tid = threadIdx.x, lane = tid & 63, wv = tid >> 6;
    int g = lane >> 4, qi = lane & 15;

    #pragma unroll
    for (int p = 0; p < 12; ++p) {
        int fid = tid + p * 256;
        int r = fid / 48, c4 = (fid % 48) * 4;
        float4 a4 = *(const float4*)&x[(size_t)(row0 + r) * 192 + c4];
        uint2 pk;
        pk.x = pack2bf(a4.x, a4.y);
        pk.y = pack2bf(a4.z, a4.w);
        *(uint2*)&alds[r][c4] = pk;
    }

    f32x4 acc[4];
    #pragma unroll
    for (int nt = 0; nt < 4; ++nt) acc[nt] = (f32x4){0.f, 0.f, 0.f, 0.f};

    for (int k0 = 0; k0 < 192; k0 += 64) {
        __syncthreads();
        #pragma unroll
        for (int p = 0; p < 2; ++p) {
            int fid = tid + p * 256;
            int j = fid >> 3, kk = (fid & 7) * 8;
            *(uint4*)&blds[j][kk] =
                *(const uint4*)&wb[(size_t)(col0 + j) * 192 + k0 + kk];
        }
        __syncthreads();
        #pragma unroll
        for (int ks = 0; ks < 2; ++ks) {
            bf16x8 af = *(const bf16x8*)&alds[wv * 16 + qi][k0 + ks * 32 + g * 8];
            #pragma unroll
            for (int nt = 0; nt < 4; ++nt) {
                bf16x8 bf = *(const bf16x8*)&blds[nt * 16 + qi][ks * 32 + g * 8];
                acc[nt] = __builtin_amdgcn_mfma_f32_16x16x32_bf16(af, bf, acc[nt], 0, 0, 0);
            }
        }
    }

    #pragma unroll
    for (int nt = 0; nt < 4; ++nt) {
        int col = col0 + nt * 16 + qi;
        int three = col / 192;
        int rem = col - three * 192;
        int h = rem >> 5, c = rem & 31;
        unsigned short* dst = (three == 0) ? qout : ((three == 1) ? kout : vout);
        float scl = (three == 0) ? SC2F : 1.0f;
        #pragma unroll
        for (int r = 0; r < 4; ++r) {
            int row = row0 + wv * 16 + 4 * g + r;
            int n = row / 1600, t = row - n * 1600;
            dst[((size_t)(n * 6 + h) * 1600 + t) * 32 + c] = f2bf(acc[nt][r] * scl);
        }
    }
}

// ---------------------------------------------------------------------------
// Kernel 2: fused attention + relational epilogue. Balanced staging: every
// thread stages 1 uint4 of K AND 4 sigma-packed V dwords (critical-path
// pack-VALU halved vs role-split). unroll-2 tau loop, register-resident P,
// l via ones-MFMA.
// ---------------------------------------------------------------------------
__global__ __launch_bounds__(256) void attn_kernel(
    const unsigned short* __restrict__ qw, const unsigned short* __restrict__ kw,
    const unsigned short* __restrict__ vw, const float* __restrict__ tt,
    const float* __restrict__ th, const int* __restrict__ hops,
    const unsigned int* __restrict__ augA, const float* __restrict__ outer,
    const float* __restrict__ alpha_p, unsigned short* __restrict__ comb)
{
    __shared__ __align__(16) unsigned short ks[2][64][40];   // K, padded rows
    __shared__ __align__(16) unsigned int vts32[2][32][34];  // V^T, sigma-permuted s-pairs
    __shared__ unsigned int tthi[127], ttlo[127];

    int b = blockIdx.x;
    int serial = (b & 7) * 150 + (b >> 3);   // XCD-contiguous nh chunks
    int nh = serial / 25;
    int qt = serial % 25;
    int h = nh % 6;
    int n = nh / 6;
    int t0 = qt * 64;

    int tid = threadIdx.x;
    int lane = tid & 63, wv = tid >> 6;
    int g = lane >> 4, qi = lane & 15;

    const unsigned short* qb = qw + (size_t)nh * 51200;
    const unsigned short* kb = kw + (size_t)nh * 51200;
    const unsigned short* vb = vw + (size_t)nh * 51200;

    if (tid < 127) {   // inline ttl hi/lo packing
        float a = tt[h * 127 + tid];
        float bm1 = tt[h * 127 + max(tid - 1, 0)];
        unsigned short ha = f2bf(a), hb = f2bf(bm1);
        tthi[tid] = (unsigned)ha | ((unsigned)hb << 16);
        ttlo[tid] = (unsigned)f2bf(a - bf2f(ha)) |
                    ((unsigned)f2bf(bm1 - bf2f(hb)) << 16);
    }

    int tq = t0 + wv * 16 + qi;
    int ft = (tq * 5243) >> 17;
    int pt = tq - ft * 25;

    bf16x8 qfrag = *(const bf16x8*)&qb[(size_t)tq * 32 + g * 8];

    // static part of B_aug (hop bias, pre-scaled th), hi+lo split
    unsigned int baug_hi[4], baug_lo[4];
    #pragma unroll
    for (int jj = 0; jj < 4; ++jj) {
        int k0 = g * 8 + 2 * jj, k1 = k0 + 1;
        float v0 = 0.f, v1 = 0.f;
        if (k0 >= 4 && k0 < 29) v0 = th[h * 5 + hops[pt * 25 + (k0 - 4)]];
        if (k1 >= 4 && k1 < 29) v1 = th[h * 5 + hops[pt * 25 + (k1 - 4)]];
        unsigned short h0 = f2bf(v0), h1 = f2bf(v1);
        unsigned short l0 = f2bf(v0 - bf2f(h0)), l1 = f2bf(v1 - bf2f(h1));
        baug_hi[jj] = (unsigned)h0 | ((unsigned)h1 << 16);
        baug_lo[jj] = (unsigned)l0 | ((unsigned)l1 << 16);
    }

    f32x4 O0 = {0.f, 0.f, 0.f, 0.f}, O1 = {0.f, 0.f, 0.f, 0.f};
    f32x4 Lacc = {0.f, 0.f, 0.f, 0.f};
    uint4v onesu = {0x3F803F80u, 0x3F803F80u, 0x3F803F80u, 0x3F803F80u};
    bf16x8 onesf = __builtin_bit_cast(bf16x8, onesu);

    const uint4v* augp = (const uint4v*)augA;

    // balanced staging indices (all 256 threads do both K and V)
    int krow = tid >> 2, kc8 = (tid & 3) * 8;             // K: 1 uint4 each
    int vpp = tid >> 3, vdq = tid & 7;                    // V: pair + d-quad
    int up = (vpp & 16) | ((vpp & 6) << 1) | ((vpp & 8) >> 2) | (vpp & 1);

    // ---- prologue: stage tile 0 into buffer 0 ----
    {
        *(uint4*)&ks[0][krow][kc8] = *(const uint4*)&kb[(size_t)krow * 32 + kc8];
        union { uint2 u; unsigned short s[4]; } a, c;
        a.u = *(const uint2*)&vb[(size_t)(2 * vpp) * 32 + vdq * 4];
        c.u = *(const uint2*)&vb[(size_t)(2 * vpp + 1) * 32 + vdq * 4];
        #pragma unroll
        for (int j = 0; j < 4; ++j)
            vts32[0][vdq * 4 + j][up] = (unsigned)a.s[j] | ((unsigned)c.s[j] << 16);
    }
    uint4v augr[4];
    #pragma unroll
    for (int sb = 0; sb < 4; ++sb) augr[sb] = augp[(size_t)sb * 64 + lane];
    __syncthreads();

    #pragma unroll 2
    for (int tau = 0; tau < 25; ++tau) {
        int cur = tau & 1, nxt = cur ^ 1;
        int s0 = tau * 64;
        bool more = (tau < 24);

        // issue next tile's loads early
        uint4 kr = {0, 0, 0, 0};
        uint2 va = {0, 0}, vc = {0, 0};
        uint4v augn[4];
        if (more) {
            kr = *(const uint4*)&kb[(size_t)(s0 + 64 + krow) * 32 + kc8];
            va = *(const uint2*)&vb[(size_t)(s0 + 64 + 2 * vpp) * 32 + vdq * 4];
            vc = *(const uint2*)&vb[(size_t)(s0 + 64 + 2 * vpp + 1) * 32 + vdq * 4];
            #pragma unroll
            for (int sb = 0; sb < 4; ++sb)
                augn[sb] = augp[(size_t)((tau + 1) * 4 + sb) * 64 + lane];
        }

        int fs0 = (s0 * 5243) >> 17;

        // dynamic ttl slots of B_aug from packed tables (g==0 lanes)
        unsigned int bh0 = baug_hi[0], bh1 = baug_hi[1];
        unsigned int bl0 = baug_lo[0], bl1 = baug_lo[1];
        if (g == 0) {
            int base = ft - fs0 + 63;
            bh0 = tthi[base]; bh1 = tthi[base - 2];
            bl0 = ttlo[base]; bl1 = ttlo[base - 2];
        }
        uint4v bhiu = {bh0, bh1, baug_hi[2], baug_hi[3]};
        uint4v blou = {bl0, bl1, baug_lo[2], baug_lo[3]};
        bf16x8 bhif = __builtin_bit_cast(bf16x8, bhiu);
        bf16x8 blof = __builtin_bit_cast(bf16x8, blou);

        // QK^T + bias via table-driven aug-MFMA
        f32x4 sfr[4];
        #pragma unroll
        for (int sb = 0; sb < 4; ++sb) {
            bf16x8 af = __builtin_bit_cast(bf16x8, augr[sb]);
            bf16x8 kf = *(const bf16x8*)&ks[cur][sb * 16 + qi][g * 8];
            f32x4 cz = {0.f, 0.f, 0.f, 0.f};
            f32x4 cb = __builtin_amdgcn_mfma_f32_16x16x32_bf16(af, blof, cz, 0, 0, 0);
            cb = __builtin_amdgcn_mfma_f32_16x16x32_bf16(af, bhif, cb, 0, 0, 0);
            sfr[sb] = __builtin_amdgcn_mfma_f32_16x16x32_bf16(kf, qfrag, cb, 0, 0, 0);
        }

        // unnormalized softmax: p = 2^sfr; keep packed P in registers
        uint2 pkk[4];
        #pragma unroll
        for (int sb = 0; sb < 4; ++sb) {
            float p0 = __builtin_exp2f(sfr[sb][0]);
            float p1 = __builtin_exp2f(sfr[sb][1]);
            float p2 = __builtin_exp2f(sfr[sb][2]);
            float p3 = __builtin_exp2f(sfr[sb][3]);
            pkk[sb].x = cvt_pk_bf16(p0, p1);
            pkk[sb].y = cvt_pk_bf16(p2, p3);
        }

        // stage-writes for tau+1 BEFORE PV
        if (more) {
            *(uint4*)&ks[nxt][krow][kc8] = kr;
            union { uint2 u; unsigned short s[4]; } a, c;
            a.u = va; c.u = vc;
            #pragma unroll
            for (int j = 0; j < 4; ++j)
                vts32[nxt][vdq * 4 + j][up] = (unsigned)a.s[j] | ((unsigned)c.s[j] << 16);
            #pragma unroll
            for (int sb = 0; sb < 4; ++sb) augr[sb] = augn[sb];
        }

        #pragma unroll
        for (int c = 0; c < 2; ++c) {
            uint4v pau = {pkk[2 * c].x, pkk[2 * c].y, pkk[2 * c + 1].x, pkk[2 * c + 1].y};
            bf16x8 paf = __builtin_bit_cast(bf16x8, pau);
            uint2 la = *(const uint2*)&vts32[cur][qi][c * 16 + 4 * g];
            uint2 lb = *(const uint2*)&vts32[cur][qi][c * 16 + 4 * g + 2];
            uint2 ha = *(const uint2*)&vts32[cur][16 + qi][c * 16 + 4 * g];
            uint2 hb = *(const uint2*)&vts32[cur][16 + qi][c * 16 + 4 * g + 2];
            uint4v u0 = {la.x, la.y, lb.x, lb.y};
            uint4v u1 = {ha.x, ha.y, hb.x, hb.y};
            bf16x8 v0f = __builtin_bit_cast(bf16x8, u0);
            bf16x8 v1f = __builtin_bit_cast(bf16x8, u1);
            O0 = __builtin_amdgcn_mfma_f32_16x16x32_bf16(paf, v0f, O0, 0, 0, 0);
            O1 = __builtin_amdgcn_mfma_f32_16x16x32_bf16(paf, v1f, O1, 0, 0, 0);
            Lacc = __builtin_amdgcn_mfma_f32_16x16x32_bf16(paf, onesf, Lacc, 0, 0, 0);
        }

        __syncthreads();
    }

    // ---- fused relational epilogue ----
    // Overlay outer[h] (25x26 f32) + V rows (100x32 bf16) onto dead ks buffer.
    float* olds = (float*)&ks[0][0][0];                       // 2600 B
    unsigned short* vl = (unsigned short*)((char*)&ks[0][0][0] + 2720);
    unsigned int* vl32 = (unsigned int*)vl;
    const unsigned int* vb32 = (const unsigned int*)vb;
    int f_lo = (t0 * 5243) >> 17;

    for (int e = tid; e < 625; e += 256)
        olds[(e / 25) * 26 + (e % 25)] = outer[h * 625 + e];
    for (int w = tid; w < 1600; w += 256) {
        int row = w >> 4, c2 = w & 15;
        int grow = min(f_lo * 25 + row, 1599);
        vl32[row * 16 + c2] = vb32[(size_t)grow * 16 + c2];
    }
    __syncthreads();

    float alpha = alpha_p[0];
    int trow = t0 + wv * 16;
    #pragma unroll
    for (int r = 0; r < 4; ++r) {
        float wr = alpha / Lacc[r];
        int t = trow + 4 * g + r;
        int ftt = (t * 5243) >> 17;
        int ptt = t - ftt * 25;
        int vbr = (ftt - f_lo) * 25;
        float rel0 = 0.f, rel1 = 0.f;
        #pragma unroll
        for (int q = 0; q < 25; ++q) {
            float ow = olds[ptt * 26 + q];
            rel0 += ow * bf2f(vl[(vbr + q) * 32 + qi]);
            rel1 += ow * bf2f(vl[(vbr + q) * 32 + 16 + qi]);
        }
        size_t cb = ((size_t)(n * 1600 + t)) * 192 + h * 32;
        comb[cb + qi] = f2bf(O0[r] * wr + rel0);
        comb[cb + 16 + qi] = f2bf(O1[r] * wr + rel1);
    }
}

// ---------------------------------------------------------------------------
// Kernel 3: final projection, bf16 MFMA GEMM. Weights pre-converted to bf16.
// ---------------------------------------------------------------------------
__global__ __launch_bounds__(256) void proj_gemm_kernel(
    const unsigned short* __restrict__ comb, const unsigned short* __restrict__ pwb,
    const float* __restrict__ pb, float* __restrict__ out)
{
    __shared__ __align__(16) unsigned short alds[64][200];
    __shared__ __align__(16) unsigned short blds[64][72];

    int b = blockIdx.x;
    int bm = b % 200, bn = b / 200;
    int row0 = bm * 64, col0 = bn * 64;
    int tid = threadIdx.x, lane = tid & 63, wv = tid >> 6;
    int g = lane >> 4, qi = lane & 15;

    #pragma unroll
    for (int p = 0; p < 6; ++p) {
        int fid = tid + p * 256;
        int r = fid / 24, c8 = (fid % 24) * 8;
        *(uint4*)&alds[r][c8] = *(const uint4*)&comb[(size_t)(row0 + r) * 192 + c8];
    }

    f32x4 acc[4];
    #pragma unroll
    for (int nt = 0; nt < 4; ++nt) acc[nt] = (f32x4){0.f, 0.f, 0.f, 0.f};

    for (int k0 = 0; k0 < 192; k0 += 64) {
        __syncthreads();
        #pragma unroll
        for (int p = 0; p < 2; ++p) {
            int fid = tid + p * 256;
            int j = fid >> 3, kk = (fid & 7) * 8;
            *(uint4*)&blds[j][kk] =
                *(const uint4*)&pwb[(size_t)(col0 + j) * 192 + k0 + kk];
        }
        __syncthreads();
        #pragma unroll
        for (int ks = 0; ks < 2; ++ks) {
            bf16x8 af = *(const bf16x8*)&alds[wv * 16 + qi][k0 + ks * 32 + g * 8];
            #pragma unroll
            for (int nt = 0; nt < 4; ++nt) {
                bf16x8 bf = *(const bf16x8*)&blds[nt * 16 + qi][ks * 32 + g * 8];
                acc[nt] = __builtin_amdgcn_mfma_f32_16x16x32_bf16(af, bf, acc[nt], 0, 0, 0);
            }
        }
    }

    #pragma unroll
    for (int nt = 0; nt < 4; ++nt) {
        int col = col0 + nt * 16 + qi;
        float bias = pb[col];
        #pragma unroll
        for (int r = 0; r < 4; ++r) {
            int row = row0 + wv * 16 + 4 * g + r;
            out[(size_t)row * 192 + col] = acc[nt][r] + bias;
        }
    }
}

// ---------------------------------------------------------------------------
extern "C" void kernel_launch(void* const* d_in, const int* in_sizes, int n_in,
                              void* d_out, int out_size, void* d_ws, size_t ws_size,
                              hipStream_t stream)
{
    const float* x      = (const float*)d_in[0];
    const float* qkv_w  = (const float*)d_in[1];
    const float* proj_w = (const float*)d_in[2];
    const float* proj_b = (const float*)d_in[3];
    const float* t_w1   = (const float*)d_in[4];
    const float* t_b1   = (const float*)d_in[5];
    const float* t_w2   = (const float*)d_in[6];
    const float* t_b2   = (const float*)d_in[7];
    const float* h_w1   = (const float*)d_in[8];
    const float* h_b1   = (const float*)d_in[9];
    const float* h_w2   = (const float*)d_in[10];
    const float* h_b2   = (const float*)d_in[11];
    const float* outer  = (const float*)d_in[12];
    const float* alpha  = (const float*)d_in[13];
    const int*   hops   = (const int*)d_in[14];
    float* out = (float*)d_out;

    char* w8 = (char*)d_ws;
    float* tt = (float*)w8;                                  // 762 f @ 0
    float* th = (float*)(w8 + 3072);                         // 30 f
    unsigned int* augA = (unsigned int*)(w8 + 10240);        // 102400 B
    unsigned short* wb  = (unsigned short*)(w8 + 112640);    // 221184 B
    unsigned short* pwb = (unsigned short*)(w8 + 333824);    // 73728 B
    unsigned short* qb = (unsigned short*)(w8 + 409600);
    unsigned short* kb = qb + 2457600;
    unsigned short* vb = kb + 2457600;
    unsigned short* comb = (unsigned short*)(w8 + 409600 + 3 * 4915200);

    prep_kernel<<<301, 256, 0, stream>>>(t_w1, t_b1, t_w2, t_b2,
                                         h_w1, h_b1, h_w2, h_b2,
                                         qkv_w, proj_w, tt, th, augA, wb, pwb);
    qkv_gemm_kernel<<<1800, 256, 0, stream>>>(x, wb, qb, kb, vb);
    attn_kernel<<<1200, 256, 0, stream>>>(qb, kb, vb, tt, th, hops, augA,
                                          outer, alpha, comb);
    proj_gemm_kernel<<<600, 256, 0, stream>>>(comb, pwb, proj_b, out);
}